// Round 1
// baseline (1630.926 us; speedup 1.0000x reference)
//
#include <hip/hip_runtime.h>

// Problem dims
#define V_SZ 50000
#define E_SZ 256
#define H_SZ 512
#define B_SZ 64
#define T_SZ 2048

// d_out offsets (floats): logits | h_new | c_new | attn
#define H_OFF    (B_SZ * V_SZ)          // 3,200,000
#define C_OFF    (H_OFF + B_SZ * H_SZ)  // 3,232,768
#define ATTN_OFF (C_OFF + B_SZ * H_SZ)  // 3,265,536

// ws layout (floats) — all regions fully written before read; no memset needed
#define WS_X    0                         // [B][768]  x = [embedded(256) | context(512)]
#define WS_HW   (WS_X + B_SZ * 768)       // [B][512]  h @ W_dec^T
#define WS_SC   (WS_HW + B_SZ * H_SZ)     // [2][B][T] score partials (j-halves)
#define WS_CTXP (WS_SC + 2 * B_SZ * T_SZ) // [16][B][512] context partials (t-chunks)
#define WS_X2   (WS_CTXP + 16 * B_SZ * H_SZ) // [B][1024] x2 = [h_new | context]
#define WS_GP   (WS_X2 + B_SZ * 1024)     // [8][B][2048] gate partials (k-chunks)
// total = 1,982,464 floats ≈ 7.6 MB

__device__ __forceinline__ float fast_tanh(float x) {
    // 1 - 2/(e^{2x}+1): saturates correctly at +/-inf, no NaN
    return 1.f - 2.f / (__expf(2.f * x) + 1.f);
}
__device__ __forceinline__ float fast_sigmoid(float x) {
    return 1.f / (1.f + __expf(-x));
}

// K1: embedded = emb[token] -> x[:, :256];  hW = h @ W_dec^T
__global__ void k1_embed_hw(const int* __restrict__ tok, const float* __restrict__ hidden,
                            const float* __restrict__ emb, const float* __restrict__ W_dec,
                            float* __restrict__ ws) {
    const int b = blockIdx.x, tid = threadIdx.x;
    __shared__ __align__(16) float sh[512];
    sh[tid]       = hidden[b * 512 + tid];
    sh[tid + 256] = hidden[b * 512 + tid + 256];
    const int t = tok[b];
    ws[WS_X + b * 768 + tid] = emb[t * 256 + tid];
    __syncthreads();
    for (int jr = tid; jr < 512; jr += 256) {
        const float* w = W_dec + jr * 512;
        float acc = 0.f;
        #pragma unroll 8
        for (int k = 0; k < 512; k += 4) {
            float4 wv = *(const float4*)(w + k);
            float4 hv = *(const float4*)(sh + k);
            acc += wv.x * hv.x + wv.y * hv.y + wv.z * hv.z + wv.w * hv.w;
        }
        ws[WS_HW + b * 512 + jr] = acc;
    }
}

// K2: scores[b,t] partial over j-half = sum_j v[j]*tanh(enc[b,t,:]·W_enc[j,:] + hW[b,j])
// Block: 64 t-rows x 256 j. Thread: 8 rows (tg=tid>>5) x 8 j (jb=tid&31, j=jb+32*jj).
// LDS stride 12 floats: 16B-aligned b128, distinct 4-aligned start banks across jb.
__global__ __launch_bounds__(256, 2)
void k2_scores(const float* __restrict__ enc, const float* __restrict__ W_enc,
               const float* __restrict__ v_attn, float* __restrict__ ws) {
    __shared__ __align__(16) float Ws[256 * 12];
    __shared__ __align__(16) float Es[64 * 8];
    const int tid = threadIdx.x;
    const int jb = tid & 31, tg = tid >> 5;
    const int t0 = blockIdx.x * 64, b = blockIdx.y, j0 = blockIdx.z * 256;

    float acc[8][8];
    #pragma unroll
    for (int r = 0; r < 8; r++)
        #pragma unroll
        for (int j = 0; j < 8; j++) acc[r][j] = 0.f;

    for (int kt = 0; kt < 512; kt += 8) {
        __syncthreads();
        #pragma unroll
        for (int q = 0; q < 2; q++) {           // W_enc tile: 256 rows x 8 k
            int f = tid + 256 * q;
            int row = f >> 1, kq = f & 1;
            float4 v = *(const float4*)(W_enc + (j0 + row) * 512 + kt + kq * 4);
            *(float4*)(Ws + row * 12 + kq * 4) = v;
        }
        if (tid < 128) {                        // enc tile: 64 rows x 8 k
            int row = tid >> 1, kq = tid & 1;
            float4 v = *(const float4*)(enc + (size_t)(b * 2048 + t0 + row) * 512 + kt + kq * 4);
            *(float4*)(Es + row * 8 + kq * 4) = v;
        }
        __syncthreads();

        float er[8][8];
        #pragma unroll
        for (int r = 0; r < 8; r++) {           // broadcast reads (free)
            float4 a = *(const float4*)(Es + (tg * 8 + r) * 8);
            float4 c = *(const float4*)(Es + (tg * 8 + r) * 8 + 4);
            er[r][0] = a.x; er[r][1] = a.y; er[r][2] = a.z; er[r][3] = a.w;
            er[r][4] = c.x; er[r][5] = c.y; er[r][6] = c.z; er[r][7] = c.w;
        }
        #pragma unroll
        for (int jj = 0; jj < 8; jj++) {
            const float* wr = Ws + (jb + 32 * jj) * 12;
            float4 w0 = *(const float4*)(wr);
            float4 w1 = *(const float4*)(wr + 4);
            float w[8] = {w0.x, w0.y, w0.z, w0.w, w1.x, w1.y, w1.z, w1.w};
            #pragma unroll
            for (int r = 0; r < 8; r++)
                #pragma unroll
                for (int k = 0; k < 8; k++) acc[r][jj] += er[r][k] * w[k];
        }
    }
    // epilogue: tanh, dot with v, reduce across jb lanes
    float s[8];
    #pragma unroll
    for (int r = 0; r < 8; r++) s[r] = 0.f;
    #pragma unroll
    for (int jj = 0; jj < 8; jj++) {
        const int j = j0 + jb + 32 * jj;
        const float hw = ws[WS_HW + b * 512 + j];
        const float vj = v_attn[j];
        #pragma unroll
        for (int r = 0; r < 8; r++)
            s[r] += vj * fast_tanh(acc[r][jj] + hw);
    }
    #pragma unroll
    for (int r = 0; r < 8; r++) {
        float v = s[r];
        #pragma unroll
        for (int m = 16; m; m >>= 1) v += __shfl_xor(v, m, 32);
        if (jb == 0)
            ws[WS_SC + blockIdx.z * (B_SZ * T_SZ) + b * 2048 + t0 + tg * 8 + r] = v;
    }
}

// K3: softmax over T per b; writes attn to d_out
__global__ void k3_softmax(const float* __restrict__ ws, float* __restrict__ out) {
    const int b = blockIdx.x, tid = threadIdx.x;
    const float* s0 = ws + WS_SC + b * 2048;
    const float* s1 = ws + WS_SC + B_SZ * T_SZ + b * 2048;
    float sv[8];
    float m = -1e30f;
    #pragma unroll
    for (int i = 0; i < 8; i++) {
        int t = tid + 256 * i;
        sv[i] = s0[t] + s1[t];
        m = fmaxf(m, sv[i]);
    }
    #pragma unroll
    for (int o = 32; o; o >>= 1) m = fmaxf(m, __shfl_xor(m, o, 64));
    __shared__ float red[4], red2[4];
    if ((tid & 63) == 0) red[tid >> 6] = m;
    __syncthreads();
    m = fmaxf(fmaxf(red[0], red[1]), fmaxf(red[2], red[3]));
    float sum = 0.f;
    #pragma unroll
    for (int i = 0; i < 8; i++) { sv[i] = __expf(sv[i] - m); sum += sv[i]; }
    #pragma unroll
    for (int o = 32; o; o >>= 1) sum += __shfl_xor(sum, o, 64);
    if ((tid & 63) == 0) red2[tid >> 6] = sum;
    __syncthreads();
    sum = red2[0] + red2[1] + red2[2] + red2[3];
    const float inv = 1.f / sum;
    #pragma unroll
    for (int i = 0; i < 8; i++) {
        int t = tid + 256 * i;
        out[ATTN_OFF + b * 2048 + t] = sv[i] * inv;
    }
}

// K4: context partials over t-chunks of 128
__global__ void k4_ctx(const float* __restrict__ enc, const float* __restrict__ attn_out,
                       float* __restrict__ ws) {
    const int ts = blockIdx.x, b = blockIdx.y, tid = threadIdx.x;
    const float* attn = attn_out + ATTN_OFF + b * 2048 + ts * 128;
    const float* ep = enc + (size_t)(b * 2048 + ts * 128) * 512 + tid * 2;
    float2 acc = {0.f, 0.f};
    #pragma unroll 4
    for (int tt = 0; tt < 128; tt++) {
        float a = attn[tt];
        float2 e = *(const float2*)(ep + (size_t)tt * 512);
        acc.x += a * e.x;
        acc.y += a * e.y;
    }
    *(float2*)(ws + WS_CTXP + (ts * 64 + b) * 512 + tid * 2) = acc;
}

// K4b: reduce 16 context partials -> x[:,256:768] and x2[:,512:1024]
__global__ void k4b_ctx_reduce(float* __restrict__ ws) {
    const int idx = blockIdx.x * 256 + threadIdx.x; // 0..32767
    const int b = idx >> 9, h = idx & 511;
    float s = 0.f;
    #pragma unroll
    for (int c = 0; c < 16; c++) s += ws[WS_CTXP + c * (B_SZ * 512) + b * 512 + h];
    ws[WS_X + b * 768 + 256 + h] = s;
    ws[WS_X2 + b * 1024 + 512 + h] = s;
}

// K5: gate partials. z = [x(768) | h(512)], W_cat = [W_ih | W_hh] (K=1280, split 8)
// Block: 64 b-rows x 128 g. Thread: 8 rows x 4 g.
__global__ __launch_bounds__(256, 2)
void k5_gates(const float* __restrict__ hidden, const float* __restrict__ W_ih,
              const float* __restrict__ W_hh, float* __restrict__ ws) {
    __shared__ __align__(16) float Wg[128 * 12];
    __shared__ __align__(16) float Zs[64 * 8];
    const int tid = threadIdx.x;
    const int jb = tid & 31, tg = tid >> 5;
    const int g0 = blockIdx.x * 128;
    const int kc = blockIdx.y;
    const int kbase = kc * 160;
    const float* xp = ws + WS_X;

    float acc[8][4];
    #pragma unroll
    for (int r = 0; r < 8; r++)
        #pragma unroll
        for (int j = 0; j < 4; j++) acc[r][j] = 0.f;

    for (int kt0 = 0; kt0 < 160; kt0 += 8) {
        const int kt = kbase + kt0;
        __syncthreads();
        {   // Wg tile: 128 rows x 8 k (one f4 per thread)
            int row = tid >> 1, kq = tid & 1;
            int k = kt + kq * 4;
            const float* src = (k < 768) ? (W_ih + (g0 + row) * 768 + k)
                                         : (W_hh + (g0 + row) * 512 + (k - 768));
            *(float4*)(Wg + row * 12 + kq * 4) = *(const float4*)src;
        }
        if (tid < 128) {  // Zs tile: 64 rows x 8 k
            int row = tid >> 1, kq = tid & 1;
            int k = kt + kq * 4;
            const float* src = (k < 768) ? (xp + row * 768 + k)
                                         : (hidden + row * 512 + (k - 768));
            *(float4*)(Zs + row * 8 + kq * 4) = *(const float4*)src;
        }
        __syncthreads();

        float er[8][8];
        #pragma unroll
        for (int r = 0; r < 8; r++) {
            float4 a = *(const float4*)(Zs + (tg * 8 + r) * 8);
            float4 c = *(const float4*)(Zs + (tg * 8 + r) * 8 + 4);
            er[r][0] = a.x; er[r][1] = a.y; er[r][2] = a.z; er[r][3] = a.w;
            er[r][4] = c.x; er[r][5] = c.y; er[r][6] = c.z; er[r][7] = c.w;
        }
        #pragma unroll
        for (int jj = 0; jj < 4; jj++) {
            const float* wr = Wg + (jb + 32 * jj) * 12;
            float4 w0 = *(const float4*)(wr);
            float4 w1 = *(const float4*)(wr + 4);
            float w[8] = {w0.x, w0.y, w0.z, w0.w, w1.x, w1.y, w1.z, w1.w};
            #pragma unroll
            for (int r = 0; r < 8; r++)
                #pragma unroll
                for (int k = 0; k < 8; k++) acc[r][jj] += er[r][k] * w[k];
        }
    }
    #pragma unroll
    for (int jj = 0; jj < 4; jj++)
        #pragma unroll
        for (int r = 0; r < 8; r++)
            ws[WS_GP + kc * (B_SZ * 2048) + (tg * 8 + r) * 2048 + g0 + jb + 32 * jj] = acc[r][jj];
}

// K5b: sum gate partials + biases, LSTM pointwise; writes h_new/c_new + x2[:, :512]
__global__ void k5b_lstm(const float* __restrict__ cell, const float* __restrict__ b_ih,
                         const float* __restrict__ b_hh, float* __restrict__ ws,
                         float* __restrict__ out) {
    const int e = blockIdx.x * 256 + threadIdx.x; // 0..32767
    const int b = e >> 9, hh = e & 511;
    float g4[4];
    #pragma unroll
    for (int q = 0; q < 4; q++) {
        float s = b_ih[q * 512 + hh] + b_hh[q * 512 + hh];
        #pragma unroll
        for (int c = 0; c < 8; c++)
            s += ws[WS_GP + c * (B_SZ * 2048) + b * 2048 + q * 512 + hh];
        g4[q] = s;
    }
    const float ig = fast_sigmoid(g4[0]);
    const float fg = fast_sigmoid(g4[1]);
    const float gg = fast_tanh(g4[2]);
    const float og = fast_sigmoid(g4[3]);
    const float c_old = cell[b * 512 + hh];
    const float c_new = fg * c_old + ig * gg;
    const float h_new = og * fast_tanh(c_new);
    out[H_OFF + b * 512 + hh] = h_new;
    out[C_OFF + b * 512 + hh] = c_new;
    ws[WS_X2 + b * 1024 + hh] = h_new;
}

// K6: logits = x2 @ W_out^T + b_out. Block: 64 b x 256 v. Same tiling as K2.
__global__ __launch_bounds__(256, 2)
void k6_logits(const float* __restrict__ W_out, const float* __restrict__ b_out,
               const float* __restrict__ ws, float* __restrict__ out) {
    __shared__ __align__(16) float Wl[256 * 12];
    __shared__ __align__(16) float Xs[64 * 8];
    const int tid = threadIdx.x;
    const int jb = tid & 31, tg = tid >> 5;
    const int v0 = blockIdx.x * 256;
    const float* x2 = ws + WS_X2;

    float acc[8][8];
    #pragma unroll
    for (int r = 0; r < 8; r++)
        #pragma unroll
        for (int j = 0; j < 8; j++) acc[r][j] = 0.f;

    for (int kt = 0; kt < 1024; kt += 8) {
        __syncthreads();
        #pragma unroll
        for (int q = 0; q < 2; q++) {
            int f = tid + 256 * q;
            int row = f >> 1, kq = f & 1;
            int v = v0 + row;
            if (v > V_SZ - 1) v = V_SZ - 1;  // clamp OOB rows; writes guarded below
            float4 w = *(const float4*)(W_out + (size_t)v * 1024 + kt + kq * 4);
            *(float4*)(Wl + row * 12 + kq * 4) = w;
        }
        if (tid < 128) {
            int row = tid >> 1, kq = tid & 1;
            float4 x = *(const float4*)(x2 + row * 1024 + kt + kq * 4);
            *(float4*)(Xs + row * 8 + kq * 4) = x;
        }
        __syncthreads();

        float er[8][8];
        #pragma unroll
        for (int r = 0; r < 8; r++) {
            float4 a = *(const float4*)(Xs + (tg * 8 + r) * 8);
            float4 c = *(const float4*)(Xs + (tg * 8 + r) * 8 + 4);
            er[r][0] = a.x; er[r][1] = a.y; er[r][2] = a.z; er[r][3] = a.w;
            er[r][4] = c.x; er[r][5] = c.y; er[r][6] = c.z; er[r][7] = c.w;
        }
        #pragma unroll
        for (int jj = 0; jj < 8; jj++) {
            const float* wr = Wl + (jb + 32 * jj) * 12;
            float4 w0 = *(const float4*)(wr);
            float4 w1 = *(const float4*)(wr + 4);
            float w[8] = {w0.x, w0.y, w0.z, w0.w, w1.x, w1.y, w1.z, w1.w};
            #pragma unroll
            for (int r = 0; r < 8; r++)
                #pragma unroll
                for (int k = 0; k < 8; k++) acc[r][jj] += er[r][k] * w[k];
        }
    }
    #pragma unroll
    for (int jj = 0; jj < 8; jj++) {
        const int v = v0 + jb + 32 * jj;
        if (v < V_SZ) {
            const float bo = b_out[v];
            #pragma unroll
            for (int r = 0; r < 8; r++) {
                const int b = tg * 8 + r;
                out[b * V_SZ + v] = acc[r][jj] + bo;
            }
        }
    }
}

extern "C" void kernel_launch(void* const* d_in, const int* in_sizes, int n_in,
                              void* d_out, int out_size, void* d_ws, size_t ws_size,
                              hipStream_t stream) {
    (void)in_sizes; (void)n_in; (void)out_size; (void)ws_size;
    const int*   tok    = (const int*)d_in[0];
    const float* hidden = (const float*)d_in[1];
    const float* cell   = (const float*)d_in[2];
    const float* enc    = (const float*)d_in[3];
    const float* emb    = (const float*)d_in[4];
    const float* W_enc  = (const float*)d_in[5];
    const float* W_dec  = (const float*)d_in[6];
    const float* v_attn = (const float*)d_in[7];
    const float* W_ih   = (const float*)d_in[8];
    const float* W_hh   = (const float*)d_in[9];
    const float* b_ih   = (const float*)d_in[10];
    const float* b_hh   = (const float*)d_in[11];
    const float* W_out  = (const float*)d_in[12];
    const float* b_out  = (const float*)d_in[13];
    float* out = (float*)d_out;
    float* ws  = (float*)d_ws;

    k1_embed_hw<<<dim3(64), dim3(256), 0, stream>>>(tok, hidden, emb, W_dec, ws);
    k2_scores<<<dim3(32, 64, 2), dim3(256), 0, stream>>>(enc, W_enc, v_attn, ws);
    k3_softmax<<<dim3(64), dim3(256), 0, stream>>>(ws, out);
    k4_ctx<<<dim3(16, 64), dim3(256), 0, stream>>>(enc, out, ws);
    k4b_ctx_reduce<<<dim3(128), dim3(256), 0, stream>>>(ws);
    k5_gates<<<dim3(16, 8), dim3(256), 0, stream>>>(hidden, W_ih, W_hh, ws);
    k5b_lstm<<<dim3(128), dim3(256), 0, stream>>>(cell, b_ih, b_hh, ws, out);
    k6_logits<<<dim3(196), dim3(256), 0, stream>>>(W_out, b_out, ws, out);
}

// Round 2
// 829.551 us; speedup vs baseline: 1.9660x; 1.9660x over previous
//
#include <hip/hip_runtime.h>

// Problem dims
#define V_SZ 50000
#define E_SZ 256
#define H_SZ 512
#define B_SZ 64
#define T_SZ 2048

// d_out offsets (floats): logits | h_new | c_new | attn
#define H_OFF    (B_SZ * V_SZ)
#define C_OFF    (H_OFF + B_SZ * H_SZ)
#define ATTN_OFF (C_OFF + B_SZ * H_SZ)

// ws layout (floats) — all regions fully written before read; no memset needed
#define WS_X    0                         // [B][768]  x = [embedded(256) | context(512)]
#define WS_HW   (WS_X + B_SZ * 768)       // [B][512]  h @ W_dec^T
#define WS_SC   (WS_HW + B_SZ * H_SZ)     // [B][T] scores (full, single copy)
#define WS_CTXP (WS_SC + B_SZ * T_SZ)     // [16][B][512] context partials
#define WS_X2   (WS_CTXP + 16 * B_SZ * H_SZ) // [B][1024] x2 = [h_new | context]
#define WS_GP   (WS_X2 + B_SZ * 1024)     // [8][B][2048] gate partials
#define WS_WB   (WS_GP + 8 * B_SZ * 2048) // W_enc as bf16: 512*512 ushort (=131072 floats)
// total = 1,982,464 floats ≈ 7.9 MB

typedef __attribute__((ext_vector_type(8))) short bf16x8;
typedef __attribute__((ext_vector_type(4))) float floatx4;

__device__ __forceinline__ float fast_tanh(float x) {
    return 1.f - 2.f / (__expf(2.f * x) + 1.f);
}
__device__ __forceinline__ float fast_sigmoid(float x) {
    return 1.f / (1.f + __expf(-x));
}
__device__ __forceinline__ unsigned short f2bf(float f) {
    union { float f; unsigned u; } v; v.f = f;
    unsigned r = v.u + 0x7FFFu + ((v.u >> 16) & 1u);  // RTN-even
    return (unsigned short)(r >> 16);
}

// K0: pre-convert W_enc (512x512 fp32) -> bf16 in ws (row-major [j][k])
__global__ void k0_wenc_bf16(const float* __restrict__ W_enc, float* __restrict__ ws) {
    unsigned short* Wb = (unsigned short*)(ws + WS_WB);
    const int i = (blockIdx.x * 256 + threadIdx.x) * 8;  // 128 blocks x 256 thr x 8
    float4 a = *(const float4*)(W_enc + i);
    float4 b = *(const float4*)(W_enc + i + 4);
    ushort4 lo = {f2bf(a.x), f2bf(a.y), f2bf(a.z), f2bf(a.w)};
    ushort4 hi = {f2bf(b.x), f2bf(b.y), f2bf(b.z), f2bf(b.w)};
    *(ushort4*)(Wb + i) = lo;
    *(ushort4*)(Wb + i + 4) = hi;
}

// K1: embedded = emb[token] -> x[:, :256];  hW = h @ W_dec^T
__global__ void k1_embed_hw(const int* __restrict__ tok, const float* __restrict__ hidden,
                            const float* __restrict__ emb, const float* __restrict__ W_dec,
                            float* __restrict__ ws) {
    const int b = blockIdx.x, tid = threadIdx.x;
    __shared__ __align__(16) float sh[512];
    sh[tid]       = hidden[b * 512 + tid];
    sh[tid + 256] = hidden[b * 512 + tid + 256];
    const int t = tok[b];
    ws[WS_X + b * 768 + tid] = emb[t * 256 + tid];
    __syncthreads();
    for (int jr = tid; jr < 512; jr += 256) {
        const float* w = W_dec + jr * 512;
        float acc = 0.f;
        #pragma unroll 8
        for (int k = 0; k < 512; k += 4) {
            float4 wv = *(const float4*)(w + k);
            float4 hv = *(const float4*)(sh + k);
            acc += wv.x * hv.x + wv.y * hv.y + wv.z * hv.z + wv.w * hv.w;
        }
        ws[WS_HW + b * 512 + jr] = acc;
    }
}

// K2: scores via bf16 MFMA. Block tile: M=64 t-rows x N=512 j x K=512, BK=32.
// 4 waves; wave w covers j in [w*128, w*128+128). Epilogue: tanh + v-dot +
// quad-lane reduce + cross-wave LDS reduce -> scores[b][t] directly.
__global__ __launch_bounds__(256, 2)
void k2_scores(const float* __restrict__ enc, const float* __restrict__ v_attn,
               float* __restrict__ ws) {
    // LDS: pad rows to 40 ushorts (80 B) -> b128 frag reads 16B-aligned, ~2-way max
    __shared__ __align__(16) unsigned short As[64 * 40];   // [t-row][k] bf16
    __shared__ __align__(16) unsigned short Bs[512 * 40];  // [j][k] bf16
    __shared__ float sp[4][64];
    const unsigned short* Wb = (const unsigned short*)(ws + WS_WB);
    const int tid = threadIdx.x;
    const int lane = tid & 63, wv = tid >> 6;
    const int lane15 = lane & 15, quad = lane >> 4;
    const int t0 = blockIdx.x * 64, b = blockIdx.y;
    const int wn = wv * 128;

    floatx4 acc[4][8];
    #pragma unroll
    for (int mt = 0; mt < 4; mt++)
        #pragma unroll
        for (int nt = 0; nt < 8; nt++) acc[mt][nt] = (floatx4){0.f, 0.f, 0.f, 0.f};

    for (int kt = 0; kt < 512; kt += 32) {
        __syncthreads();
        // A tile: 64 rows x 32 k fp32 -> bf16 (2 float4 per thread)
        #pragma unroll
        for (int q = 0; q < 2; q++) {
            int f = tid + 256 * q;
            int row = f >> 3, kq = f & 7;
            float4 v = *(const float4*)(enc + (size_t)(b * 2048 + t0 + row) * 512 + kt + kq * 4);
            ushort4 h = {f2bf(v.x), f2bf(v.y), f2bf(v.z), f2bf(v.w)};
            *(ushort4*)(As + row * 40 + kq * 4) = h;
        }
        // B tile: 512 j x 32 k bf16 (8 x uint4 per thread)
        #pragma unroll
        for (int q = 0; q < 8; q++) {
            int f = tid + 256 * q;
            int row = f >> 2, c = f & 3;
            uint4 w = *(const uint4*)(Wb + row * 512 + kt + c * 8);
            *(uint4*)(Bs + row * 40 + c * 8) = w;
        }
        __syncthreads();

        bf16x8 af[4];
        #pragma unroll
        for (int mt = 0; mt < 4; mt++)
            af[mt] = *(const bf16x8*)(As + (mt * 16 + lane15) * 40 + quad * 8);
        #pragma unroll
        for (int nt = 0; nt < 8; nt++) {
            bf16x8 bf = *(const bf16x8*)(Bs + (wn + nt * 16 + lane15) * 40 + quad * 8);
            #pragma unroll
            for (int mt = 0; mt < 4; mt++)
                acc[mt][nt] = __builtin_amdgcn_mfma_f32_16x16x32_bf16(af[mt], bf, acc[mt][nt], 0, 0, 0);
        }
    }

    // epilogue
    float vj[8], hwj[8];
    #pragma unroll
    for (int nt = 0; nt < 8; nt++) {
        int jg = wn + nt * 16 + lane15;
        vj[nt] = v_attn[jg];
        hwj[nt] = ws[WS_HW + b * 512 + jg];
    }
    #pragma unroll
    for (int mt = 0; mt < 4; mt++) {
        #pragma unroll
        for (int reg = 0; reg < 4; reg++) {
            int row = mt * 16 + quad * 4 + reg;
            float s = 0.f;
            #pragma unroll
            for (int nt = 0; nt < 8; nt++)
                s += vj[nt] * fast_tanh(acc[mt][nt][reg] + hwj[nt]);
            #pragma unroll
            for (int off = 8; off; off >>= 1) s += __shfl_xor(s, off);
            if (lane15 == 0) sp[wv][row] = s;
        }
    }
    __syncthreads();
    if (tid < 64)
        ws[WS_SC + b * 2048 + t0 + tid] = sp[0][tid] + sp[1][tid] + sp[2][tid] + sp[3][tid];
}

// K3: softmax over T per b; writes attn to d_out
__global__ void k3_softmax(const float* __restrict__ ws, float* __restrict__ out) {
    const int b = blockIdx.x, tid = threadIdx.x;
    const float* s0 = ws + WS_SC + b * 2048;
    float sv[8];
    float m = -1e30f;
    #pragma unroll
    for (int i = 0; i < 8; i++) {
        int t = tid + 256 * i;
        sv[i] = s0[t];
        m = fmaxf(m, sv[i]);
    }
    #pragma unroll
    for (int o = 32; o; o >>= 1) m = fmaxf(m, __shfl_xor(m, o, 64));
    __shared__ float red[4], red2[4];
    if ((tid & 63) == 0) red[tid >> 6] = m;
    __syncthreads();
    m = fmaxf(fmaxf(red[0], red[1]), fmaxf(red[2], red[3]));
    float sum = 0.f;
    #pragma unroll
    for (int i = 0; i < 8; i++) { sv[i] = __expf(sv[i] - m); sum += sv[i]; }
    #pragma unroll
    for (int o = 32; o; o >>= 1) sum += __shfl_xor(sum, o, 64);
    if ((tid & 63) == 0) red2[tid >> 6] = sum;
    __syncthreads();
    sum = red2[0] + red2[1] + red2[2] + red2[3];
    const float inv = 1.f / sum;
    #pragma unroll
    for (int i = 0; i < 8; i++) {
        int t = tid + 256 * i;
        out[ATTN_OFF + b * 2048 + t] = sv[i] * inv;
    }
}

// K4: context partials over t-chunks of 128
__global__ void k4_ctx(const float* __restrict__ enc, const float* __restrict__ attn_out,
                       float* __restrict__ ws) {
    const int ts = blockIdx.x, b = blockIdx.y, tid = threadIdx.x;
    const float* attn = attn_out + ATTN_OFF + b * 2048 + ts * 128;
    const float* ep = enc + (size_t)(b * 2048 + ts * 128) * 512 + tid * 2;
    float2 acc = {0.f, 0.f};
    #pragma unroll 4
    for (int tt = 0; tt < 128; tt++) {
        float a = attn[tt];
        float2 e = *(const float2*)(ep + (size_t)tt * 512);
        acc.x += a * e.x;
        acc.y += a * e.y;
    }
    *(float2*)(ws + WS_CTXP + (ts * 64 + b) * 512 + tid * 2) = acc;
}

// K4b: reduce 16 context partials -> x[:,256:768] and x2[:,512:1024]
__global__ void k4b_ctx_reduce(float* __restrict__ ws) {
    const int idx = blockIdx.x * 256 + threadIdx.x;
    const int b = idx >> 9, h = idx & 511;
    float s = 0.f;
    #pragma unroll
    for (int c = 0; c < 16; c++) s += ws[WS_CTXP + c * (B_SZ * 512) + b * 512 + h];
    ws[WS_X + b * 768 + 256 + h] = s;
    ws[WS_X2 + b * 1024 + 512 + h] = s;
}

// K5: gate partials (fp32 register-tiled GEMM, small: 64x2048x1280)
__global__ __launch_bounds__(256, 2)
void k5_gates(const float* __restrict__ hidden, const float* __restrict__ W_ih,
              const float* __restrict__ W_hh, float* __restrict__ ws) {
    __shared__ __align__(16) float Wg[128 * 12];
    __shared__ __align__(16) float Zs[64 * 8];
    const int tid = threadIdx.x;
    const int jb = tid & 31, tg = tid >> 5;
    const int g0 = blockIdx.x * 128;
    const int kc = blockIdx.y;
    const int kbase = kc * 160;
    const float* xp = ws + WS_X;

    float acc[8][4];
    #pragma unroll
    for (int r = 0; r < 8; r++)
        #pragma unroll
        for (int j = 0; j < 4; j++) acc[r][j] = 0.f;

    for (int kt0 = 0; kt0 < 160; kt0 += 8) {
        const int kt = kbase + kt0;
        __syncthreads();
        {
            int row = tid >> 1, kq = tid & 1;
            int k = kt + kq * 4;
            const float* src = (k < 768) ? (W_ih + (g0 + row) * 768 + k)
                                         : (W_hh + (g0 + row) * 512 + (k - 768));
            *(float4*)(Wg + row * 12 + kq * 4) = *(const float4*)src;
        }
        if (tid < 128) {
            int row = tid >> 1, kq = tid & 1;
            int k = kt + kq * 4;
            const float* src = (k < 768) ? (xp + row * 768 + k)
                                         : (hidden + row * 512 + (k - 768));
            *(float4*)(Zs + row * 8 + kq * 4) = *(const float4*)src;
        }
        __syncthreads();

        float er[8][8];
        #pragma unroll
        for (int r = 0; r < 8; r++) {
            float4 a = *(const float4*)(Zs + (tg * 8 + r) * 8);
            float4 c = *(const float4*)(Zs + (tg * 8 + r) * 8 + 4);
            er[r][0] = a.x; er[r][1] = a.y; er[r][2] = a.z; er[r][3] = a.w;
            er[r][4] = c.x; er[r][5] = c.y; er[r][6] = c.z; er[r][7] = c.w;
        }
        #pragma unroll
        for (int jj = 0; jj < 4; jj++) {
            const float* wr = Wg + (jb + 32 * jj) * 12;
            float4 w0 = *(const float4*)(wr);
            float4 w1 = *(const float4*)(wr + 4);
            float w[8] = {w0.x, w0.y, w0.z, w0.w, w1.x, w1.y, w1.z, w1.w};
            #pragma unroll
            for (int r = 0; r < 8; r++)
                #pragma unroll
                for (int k = 0; k < 8; k++) acc[r][jj] += er[r][k] * w[k];
        }
    }
    #pragma unroll
    for (int jj = 0; jj < 4; jj++)
        #pragma unroll
        for (int r = 0; r < 8; r++)
            ws[WS_GP + kc * (B_SZ * 2048) + (tg * 8 + r) * 2048 + g0 + jb + 32 * jj] = acc[r][jj];
}

// K5b: sum gate partials + biases, LSTM pointwise
__global__ void k5b_lstm(const float* __restrict__ cell, const float* __restrict__ b_ih,
                         const float* __restrict__ b_hh, float* __restrict__ ws,
                         float* __restrict__ out) {
    const int e = blockIdx.x * 256 + threadIdx.x;
    const int b = e >> 9, hh = e & 511;
    float g4[4];
    #pragma unroll
    for (int q = 0; q < 4; q++) {
        float s = b_ih[q * 512 + hh] + b_hh[q * 512 + hh];
        #pragma unroll
        for (int c = 0; c < 8; c++)
            s += ws[WS_GP + c * (B_SZ * 2048) + b * 2048 + q * 512 + hh];
        g4[q] = s;
    }
    const float ig = fast_sigmoid(g4[0]);
    const float fg = fast_sigmoid(g4[1]);
    const float gg = fast_tanh(g4[2]);
    const float og = fast_sigmoid(g4[3]);
    const float c_old = cell[b * 512 + hh];
    const float c_new = fg * c_old + ig * gg;
    const float h_new = og * fast_tanh(c_new);
    out[H_OFF + b * 512 + hh] = h_new;
    out[C_OFF + b * 512 + hh] = c_new;
    ws[WS_X2 + b * 1024 + hh] = h_new;
}

// K6: logits via bf16 MFMA. Block tile M=64 b x N=256 v x K=1024, BK=32.
// W_out rows are read exactly once -> convert fp32->bf16 in-block.
__global__ __launch_bounds__(256, 2)
void k6_logits(const float* __restrict__ W_out, const float* __restrict__ b_out,
               const float* __restrict__ ws, float* __restrict__ out) {
    __shared__ __align__(16) unsigned short Xs[64 * 40];   // [b-row][k]
    __shared__ __align__(16) unsigned short Ws2[256 * 40]; // [v-row][k]
    const float* x2 = ws + WS_X2;
    const int tid = threadIdx.x;
    const int lane = tid & 63, wv = tid >> 6;
    const int lane15 = lane & 15, quad = lane >> 4;
    const int v0 = blockIdx.x * 256;
    const int wn = wv * 64;

    floatx4 acc[4][4];
    #pragma unroll
    for (int mt = 0; mt < 4; mt++)
        #pragma unroll
        for (int nt = 0; nt < 4; nt++) acc[mt][nt] = (floatx4){0.f, 0.f, 0.f, 0.f};

    for (int kt = 0; kt < 1024; kt += 32) {
        __syncthreads();
        #pragma unroll
        for (int q = 0; q < 2; q++) {  // x2 tile
            int f = tid + 256 * q;
            int row = f >> 3, kq = f & 7;
            float4 v = *(const float4*)(x2 + row * 1024 + kt + kq * 4);
            ushort4 h = {f2bf(v.x), f2bf(v.y), f2bf(v.z), f2bf(v.w)};
            *(ushort4*)(Xs + row * 40 + kq * 4) = h;
        }
        #pragma unroll
        for (int q = 0; q < 8; q++) {  // W_out tile (256 rows x 32 k)
            int f = tid + 256 * q;
            int row = f >> 3, kq = f & 7;
            int v = v0 + row; if (v > V_SZ - 1) v = V_SZ - 1;
            float4 w = *(const float4*)(W_out + (size_t)v * 1024 + kt + kq * 4);
            ushort4 h = {f2bf(w.x), f2bf(w.y), f2bf(w.z), f2bf(w.w)};
            *(ushort4*)(Ws2 + row * 40 + kq * 4) = h;
        }
        __syncthreads();

        bf16x8 af[4];
        #pragma unroll
        for (int mt = 0; mt < 4; mt++)
            af[mt] = *(const bf16x8*)(Xs + (mt * 16 + lane15) * 40 + quad * 8);
        #pragma unroll
        for (int nt = 0; nt < 4; nt++) {
            bf16x8 bf = *(const bf16x8*)(Ws2 + (wn + nt * 16 + lane15) * 40 + quad * 8);
            #pragma unroll
            for (int mt = 0; mt < 4; mt++)
                acc[mt][nt] = __builtin_amdgcn_mfma_f32_16x16x32_bf16(af[mt], bf, acc[mt][nt], 0, 0, 0);
        }
    }

    #pragma unroll
    for (int nt = 0; nt < 4; nt++) {
        const int v = v0 + wn + nt * 16 + lane15;
        if (v < V_SZ) {
            const float bo = b_out[v];
            #pragma unroll
            for (int mt = 0; mt < 4; mt++)
                #pragma unroll
                for (int reg = 0; reg < 4; reg++) {
                    const int br = mt * 16 + quad * 4 + reg;
                    out[br * V_SZ + v] = acc[mt][nt][reg] + bo;
                }
        }
    }
}

extern "C" void kernel_launch(void* const* d_in, const int* in_sizes, int n_in,
                              void* d_out, int out_size, void* d_ws, size_t ws_size,
                              hipStream_t stream) {
    (void)in_sizes; (void)n_in; (void)out_size; (void)ws_size;
    const int*   tok    = (const int*)d_in[0];
    const float* hidden = (const float*)d_in[1];
    const float* cell   = (const float*)d_in[2];
    const float* enc    = (const float*)d_in[3];
    const float* emb    = (const float*)d_in[4];
    const float* W_enc  = (const float*)d_in[5];
    const float* W_dec  = (const float*)d_in[6];
    const float* v_attn = (const float*)d_in[7];
    const float* W_ih   = (const float*)d_in[8];
    const float* W_hh   = (const float*)d_in[9];
    const float* b_ih   = (const float*)d_in[10];
    const float* b_hh   = (const float*)d_in[11];
    const float* W_out  = (const float*)d_in[12];
    const float* b_out  = (const float*)d_in[13];
    float* out = (float*)d_out;
    float* ws  = (float*)d_ws;

    k0_wenc_bf16<<<dim3(128), dim3(256), 0, stream>>>(W_enc, ws);
    k1_embed_hw<<<dim3(64), dim3(256), 0, stream>>>(tok, hidden, emb, W_dec, ws);
    k2_scores<<<dim3(32, 64), dim3(256), 0, stream>>>(enc, v_attn, ws);
    k3_softmax<<<dim3(64), dim3(256), 0, stream>>>(ws, out);
    k4_ctx<<<dim3(16, 64), dim3(256), 0, stream>>>(enc, out, ws);
    k4b_ctx_reduce<<<dim3(128), dim3(256), 0, stream>>>(ws);
    k5_gates<<<dim3(16, 8), dim3(256), 0, stream>>>(hidden, W_ih, W_hh, ws);
    k5b_lstm<<<dim3(128), dim3(256), 0, stream>>>(cell, b_ih, b_hh, ws, out);
    k6_logits<<<dim3(196), dim3(256), 0, stream>>>(W_out, b_out, ws, out);
}